// Round 4
// baseline (309.427 us; speedup 1.0000x reference)
//
#include <hip/hip_runtime.h>
#include <math.h>

#define B_ 64
#define N_ 8192
#define W_ 64
#define H_ 4
#define CTRL_ 280
#define EPS_ 1e-8f

__device__ __forceinline__ float softplusf(float x) {
    return fmaxf(x, 0.f) + log1pf(expf(-fabsf(x)));
}

__device__ __forceinline__ float waveReduceSum(float v) {
    #pragma unroll
    for (int m = 1; m < 64; m <<= 1) v += __shfl_xor(v, m, 64);
    return v;
}

// ---------------- K1: content scores -> e = exp(score - beta), L atomics ----
// grid (N/64, B), block 256. e layout [B][H][N].
// softmax(s) == exp(s - beta)/sum(exp(s - beta)) since |s| <= beta.
__global__ __launch_bounds__(256) void k_scores(const float* __restrict__ mem,
                                                const float* __restrict__ ctrl,
                                                float* __restrict__ e,
                                                float* __restrict__ L) {
    __shared__ float keys[H_ * 68];
    __shared__ float knorm[H_];
    __shared__ float beta[H_];
    __shared__ float sstage[H_ * 65];

    const int t  = threadIdx.x;
    const int b  = blockIdx.y;
    const int n0 = blockIdx.x * 64;

    // keys (tanh) + per-head key norms; wave h handles head h
    {
        int h = t >> 6, w = t & 63;
        float kv = tanhf(ctrl[b * CTRL_ + h * W_ + w]);
        keys[h * 68 + w] = kv;
        float ss = waveReduceSum(kv * kv);
        if (w == 0) knorm[h] = sqrtf(ss);
        if (t < H_) beta[t] = softplusf(ctrl[b * CTRL_ + H_ * W_ + t]);
    }
    __syncthreads();

    // thread t: row t>>2, head t&3; row read straight from global (quad-share)
    {
        int row = t >> 2, h = t & 3;
        const float4* mrow = reinterpret_cast<const float4*>(
            mem + ((size_t)b * N_ + n0 + row) * W_);
        const float4* krow = reinterpret_cast<const float4*>(&keys[h * 68]);
        float dot = 0.f, ss = 0.f;
        #pragma unroll
        for (int wg = 0; wg < 16; ++wg) {
            float4 mv = mrow[wg];
            float4 kv = krow[wg];
            dot += mv.x * kv.x + mv.y * kv.y + mv.z * kv.z + mv.w * kv.w;
            ss  += mv.x * mv.x + mv.y * mv.y + mv.z * mv.z + mv.w * mv.w;
        }
        float bh_ = beta[h];
        float sc = dot / (sqrtf(ss) * knorm[h] + EPS_) * bh_;
        sstage[h * 65 + row] = expf(sc - bh_);
    }
    __syncthreads();

    // coalesced per-head writes + per-(b,h) partial softmax denominator
    {
        int h = t >> 6, r = t & 63;
        float ev = sstage[h * 65 + r];
        e[((size_t)(b * H_ + h)) * N_ + n0 + r] = ev;
        float s = waveReduceSum(ev);
        if (r == 0) atomicAdd(&L[b * H_ + h], s);
    }
}

// ---------------- K_fused: weight chain + unnormalized read -----------------
// grid (N/256, B), block 256. Wave wv handles head wv for the weight chain
// (4 n per lane), then all 4 waves do the 256-row read accumulating into
// out_unnorm (normalization by S deferred to k_final).
__global__ __launch_bounds__(256) void k_fused(const float* __restrict__ mem,
                                               const float* __restrict__ ctrl,
                                               const float* __restrict__ prev,
                                               const float* __restrict__ e,
                                               const float* __restrict__ L,
                                               float* __restrict__ S,
                                               float* __restrict__ ounorm) {
    __shared__ float uLDS[H_ * 256];
    __shared__ float partial[16 * 64];

    const int t  = threadIdx.x;
    const int b  = blockIdx.y;
    const int cb = blockIdx.x * 256;
    const int wv = t >> 6, l = t & 63;

    // ---- weight chain: wave wv == head ----
    {
        const int h  = wv;
        const int bh = b * H_ + h;
        const size_t base = (size_t)bh * N_;

        float4 ev = *reinterpret_cast<const float4*>(e    + base + cb + l * 4);
        float4 pv = *reinterpret_cast<const float4*>(prev + base + cb + l * 4);
        float invL = 1.f / L[bh];

        const float* cp = ctrl + b * CTRL_;
        float g  = 1.f / (1.f + expf(-cp[260 + h]));
        float r0 = cp[264 + 3 * h], r1 = cp[265 + 3 * h], r2 = cp[266 + 3 * h];
        float rm = fmaxf(r0, fmaxf(r1, r2));
        float e0 = expf(r0 - rm), e1 = expf(r1 - rm), e2 = expf(r2 - rm);
        float ers = 1.f / (e0 + e1 + e2);
        float s0f = e0 * ers, s1f = e1 * ers, s2f = e2 * ers;
        float gamma = 1.f + softplusf(cp[276 + h]);
        float gi = 1.f - g;

        float wi0 = g * (ev.x * invL) + gi * pv.x;
        float wi1 = g * (ev.y * invL) + gi * pv.y;
        float wi2 = g * (ev.z * invL) + gi * pv.z;
        float wi3 = g * (ev.w * invL) + gi * pv.w;

        // halo: intra-wave shuffles; chunk boundary recomputed from global
        float wl = __shfl_up(wi3, 1, 64);
        float wr = __shfl_down(wi0, 1, 64);
        if (l == 0) {
            int nl = (cb - 1 + N_) & (N_ - 1);
            wl = g * (e[base + nl] * invL) + gi * prev[base + nl];
        }
        if (l == 63) {
            int nr = (cb + 256) & (N_ - 1);
            wr = g * (e[base + nr] * invL) + gi * prev[base + nr];
        }

        float u0 = powf(s0f * wl  + s1f * wi0 + s2f * wi1, gamma);
        float u1 = powf(s0f * wi0 + s1f * wi1 + s2f * wi2, gamma);
        float u2 = powf(s0f * wi1 + s1f * wi2 + s2f * wi3, gamma);
        float u3 = powf(s0f * wi2 + s1f * wi3 + s2f * wr,  gamma);

        float su = waveReduceSum(u0 + u1 + u2 + u3);
        if (l == 0) atomicAdd(&S[bh], su);

        float4 uo; uo.x = u0; uo.y = u1; uo.z = u2; uo.w = u3;
        *reinterpret_cast<float4*>(&uLDS[h * 256 + l * 4]) = uo;
    }
    __syncthreads();

    // ---- read: wave wv owns 64 rows of the chunk ----
    const int rb = wv * 64;
    float acc[4][4] = {};
    const float4* gb = reinterpret_cast<const float4*>(mem + ((size_t)b * N_ + cb) * W_);

    #pragma unroll 4
    for (int it = 0; it < 16; ++it) {
        int r  = rb + it * 4 + (l >> 4);
        float4 mv = gb[(size_t)r * 16 + (l & 15)];   // 1 KiB contiguous per wave instr
        #pragma unroll
        for (int h = 0; h < 4; ++h) {
            float uh = uLDS[h * 256 + r];            // 16-lane broadcast
            acc[h][0] += mv.x * uh; acc[h][1] += mv.y * uh;
            acc[h][2] += mv.z * uh; acc[h][3] += mv.w * uh;
        }
    }

    #pragma unroll
    for (int h = 0; h < 4; ++h) {
        #pragma unroll
        for (int j = 0; j < 4; ++j) {
            acc[h][j] += __shfl_xor(acc[h][j], 16, 64);
            acc[h][j] += __shfl_xor(acc[h][j], 32, 64);
        }
    }
    if (l < 16) {
        int c0 = l << 2;
        #pragma unroll
        for (int h = 0; h < 4; ++h)
            #pragma unroll
            for (int j = 0; j < 4; ++j)
                partial[(wv * 4 + h) * 64 + c0 + j] = acc[h][j];
    }
    __syncthreads();

    {
        int h = t >> 6, w = t & 63;
        float sum = partial[(0 * 4 + h) * 64 + w] + partial[(1 * 4 + h) * 64 + w]
                  + partial[(2 * 4 + h) * 64 + w] + partial[(3 * 4 + h) * 64 + w];
        atomicAdd(&ounorm[(size_t)(b * H_ + h) * W_ + w], sum);
    }
}

// ---------------- K_final: normalize by (S + eps) ---------------------------
// grid (64), block 256: out[bh][w] = ounorm[bh][w] / (S[bh] + eps)
__global__ __launch_bounds__(256) void k_final(const float* __restrict__ ounorm,
                                               const float* __restrict__ S,
                                               float* __restrict__ out) {
    int idx = blockIdx.x * 256 + threadIdx.x;
    int bh  = idx >> 6;
    out[idx] = ounorm[idx] / (S[bh] + EPS_);
}

extern "C" void kernel_launch(void* const* d_in, const int* in_sizes, int n_in,
                              void* d_out, int out_size, void* d_ws, size_t ws_size,
                              hipStream_t stream) {
    const float* mem  = (const float*)d_in[0];   // [B, N, W]
    const float* ctrl = (const float*)d_in[1];   // [B, 280]
    const float* prev = (const float*)d_in[2];   // [B, H, N]
    float* out = (float*)d_out;                  // [B, H, W] f32

    float* e      = (float*)d_ws;                    // 8 MiB
    float* L      = e + (size_t)B_ * H_ * N_;        // 256 floats
    float* S      = L + B_ * H_;                     // 256 floats
    float* ounorm = S + B_ * H_;                     // 16384 floats

    // zero L, S, ounorm (68 KB)
    hipMemsetAsync(L, 0, sizeof(float) * (2 * B_ * H_ + B_ * H_ * W_), stream);
    k_scores<<<dim3(N_ / 64, B_), 256, 0, stream>>>(mem, ctrl, e, L);
    k_fused <<<dim3(N_ / 256, B_), 256, 0, stream>>>(mem, ctrl, prev, e, L, S, ounorm);
    k_final <<<dim3(B_ * H_ * W_ / 256), 256, 0, stream>>>(ounorm, S, out);
}

// Round 5
// 222.508 us; speedup vs baseline: 1.3906x; 1.3906x over previous
//
#include <hip/hip_runtime.h>
#include <math.h>

#define B_ 64
#define N_ 8192
#define W_ 64
#define H_ 4
#define CTRL_ 280
#define EPS_ 1e-8f
#define CHUNKS_ 32            // N_/256
#define K1B_ 128              // k_scores blocks per batch (N_/64)

__device__ __forceinline__ float softplusf(float x) {
    return fmaxf(x, 0.f) + log1pf(expf(-fabsf(x)));
}

__device__ __forceinline__ float waveReduceSum(float v) {
    #pragma unroll
    for (int m = 1; m < 64; m <<= 1) v += __shfl_xor(v, m, 64);
    return v;
}

// ---------------- K1: content scores -> e = exp(score - beta) ---------------
// grid (N/64, B), block 256. e layout [B][H][N].
// Per-block partial softmax denominators -> Lpart[bh][block] (plain store,
// NO atomics: fp32 atomicAdd is a CAS loop and serialized 2x this kernel in R4).
__global__ __launch_bounds__(256) void k_scores(const float* __restrict__ mem,
                                                const float* __restrict__ ctrl,
                                                float* __restrict__ e,
                                                float* __restrict__ Lpart) {
    __shared__ float keys[H_ * 68];
    __shared__ float knorm[H_];
    __shared__ float beta[H_];
    __shared__ float sstage[H_ * 65];

    const int t  = threadIdx.x;
    const int b  = blockIdx.y;
    const int n0 = blockIdx.x * 64;

    // keys (tanh) + per-head key norms; wave h handles head h
    {
        int h = t >> 6, w = t & 63;
        float kv = tanhf(ctrl[b * CTRL_ + h * W_ + w]);
        keys[h * 68 + w] = kv;
        float ss = waveReduceSum(kv * kv);
        if (w == 0) knorm[h] = sqrtf(ss);
        if (t < H_) beta[t] = softplusf(ctrl[b * CTRL_ + H_ * W_ + t]);
    }
    __syncthreads();

    // thread t: row t>>2, head t&3. Prefetch the full row into registers so
    // all 16 loads are in flight at once (R4 had VGPR=28 -> ~2 in flight).
    {
        int row = t >> 2, h = t & 3;
        const float4* mrow = reinterpret_cast<const float4*>(
            mem + ((size_t)b * N_ + n0 + row) * W_);
        const float4* krow = reinterpret_cast<const float4*>(&keys[h * 68]);

        float4 mv[16];
        #pragma unroll
        for (int wg = 0; wg < 16; ++wg) mv[wg] = mrow[wg];

        float dot = 0.f, ss = 0.f;
        #pragma unroll
        for (int wg = 0; wg < 16; ++wg) {
            float4 kv = krow[wg];
            dot += mv[wg].x * kv.x + mv[wg].y * kv.y + mv[wg].z * kv.z + mv[wg].w * kv.w;
            ss  += mv[wg].x * mv[wg].x + mv[wg].y * mv[wg].y
                 + mv[wg].z * mv[wg].z + mv[wg].w * mv[wg].w;
        }
        float bh_ = beta[h];
        float sc = dot / (sqrtf(ss) * knorm[h] + EPS_) * bh_;
        sstage[h * 65 + row] = expf(sc - bh_);
    }
    __syncthreads();

    // coalesced per-head writes + per-block partial denominator (plain store)
    {
        int h = t >> 6, r = t & 63;
        float ev = sstage[h * 65 + r];
        e[((size_t)(b * H_ + h)) * N_ + n0 + r] = ev;
        float s = waveReduceSum(ev);
        if (r == 0) Lpart[(b * H_ + h) * K1B_ + blockIdx.x] = s;
    }
}

// ---------------- K_fused: weight chain + unnormalized read -----------------
// grid (CHUNKS_, B), block 256. Wave wv == head wv for the weight chain
// (4 n per lane); then all 4 waves do the 256-row read. Partial outputs go to
// opart[b][chunk][h*64+w] and Spart[bh][chunk] (plain stores, no atomics).
__global__ __launch_bounds__(256) void k_fused(const float* __restrict__ mem,
                                               const float* __restrict__ ctrl,
                                               const float* __restrict__ prev,
                                               const float* __restrict__ e,
                                               const float* __restrict__ Lpart,
                                               float* __restrict__ Spart,
                                               float* __restrict__ opart) {
    __shared__ float uLDS[H_ * 256];
    __shared__ float partial[16 * 64];

    const int t     = threadIdx.x;
    const int b     = blockIdx.y;
    const int chunk = blockIdx.x;
    const int cb    = chunk * 256;
    const int wv = t >> 6, l = t & 63;

    // ---- weight chain: wave wv == head ----
    {
        const int h  = wv;
        const int bh = b * H_ + h;
        const size_t base = (size_t)bh * N_;

        // reduce this head's softmax denominator from the 128 k_scores partials
        float lp = Lpart[bh * K1B_ + l] + Lpart[bh * K1B_ + 64 + l];
        float Lsum = waveReduceSum(lp);
        float invL = 1.f / Lsum;

        float4 ev = *reinterpret_cast<const float4*>(e    + base + cb + l * 4);
        float4 pv = *reinterpret_cast<const float4*>(prev + base + cb + l * 4);

        const float* cp = ctrl + b * CTRL_;
        float g  = 1.f / (1.f + expf(-cp[260 + h]));
        float r0 = cp[264 + 3 * h], r1 = cp[265 + 3 * h], r2 = cp[266 + 3 * h];
        float rm = fmaxf(r0, fmaxf(r1, r2));
        float e0 = expf(r0 - rm), e1 = expf(r1 - rm), e2 = expf(r2 - rm);
        float ers = 1.f / (e0 + e1 + e2);
        float s0f = e0 * ers, s1f = e1 * ers, s2f = e2 * ers;
        float gamma = 1.f + softplusf(cp[276 + h]);
        float gi = 1.f - g;

        float wi0 = g * (ev.x * invL) + gi * pv.x;
        float wi1 = g * (ev.y * invL) + gi * pv.y;
        float wi2 = g * (ev.z * invL) + gi * pv.z;
        float wi3 = g * (ev.w * invL) + gi * pv.w;

        // halo: intra-wave shuffles; chunk boundary recomputed from global
        float wl = __shfl_up(wi3, 1, 64);
        float wr = __shfl_down(wi0, 1, 64);
        if (l == 0) {
            int nl = (cb - 1 + N_) & (N_ - 1);
            wl = g * (e[base + nl] * invL) + gi * prev[base + nl];
        }
        if (l == 63) {
            int nr = (cb + 256) & (N_ - 1);
            wr = g * (e[base + nr] * invL) + gi * prev[base + nr];
        }

        float u0 = powf(s0f * wl  + s1f * wi0 + s2f * wi1, gamma);
        float u1 = powf(s0f * wi0 + s1f * wi1 + s2f * wi2, gamma);
        float u2 = powf(s0f * wi1 + s1f * wi2 + s2f * wi3, gamma);
        float u3 = powf(s0f * wi2 + s1f * wi3 + s2f * wr,  gamma);

        float su = waveReduceSum(u0 + u1 + u2 + u3);
        if (l == 0) Spart[bh * CHUNKS_ + chunk] = su;

        float4 uo; uo.x = u0; uo.y = u1; uo.z = u2; uo.w = u3;
        *reinterpret_cast<float4*>(&uLDS[h * 256 + l * 4]) = uo;
    }
    __syncthreads();

    // ---- read: wave wv owns 64 rows of the chunk ----
    const int rb = wv * 64;
    float acc[4][4] = {};
    const float4* gb = reinterpret_cast<const float4*>(mem + ((size_t)b * N_ + cb) * W_);

    #pragma unroll 4
    for (int it = 0; it < 16; ++it) {
        int r  = rb + it * 4 + (l >> 4);
        float4 mv = gb[(size_t)r * 16 + (l & 15)];   // 1 KiB contiguous per wave instr
        #pragma unroll
        for (int h = 0; h < 4; ++h) {
            float uh = uLDS[h * 256 + r];            // 16-lane broadcast
            acc[h][0] += mv.x * uh; acc[h][1] += mv.y * uh;
            acc[h][2] += mv.z * uh; acc[h][3] += mv.w * uh;
        }
    }

    #pragma unroll
    for (int h = 0; h < 4; ++h) {
        #pragma unroll
        for (int j = 0; j < 4; ++j) {
            acc[h][j] += __shfl_xor(acc[h][j], 16, 64);
            acc[h][j] += __shfl_xor(acc[h][j], 32, 64);
        }
    }
    if (l < 16) {
        int c0 = l << 2;
        #pragma unroll
        for (int h = 0; h < 4; ++h)
            #pragma unroll
            for (int j = 0; j < 4; ++j)
                partial[(wv * 4 + h) * 64 + c0 + j] = acc[h][j];
    }
    __syncthreads();

    // per-chunk partial output (plain store, coalesced)
    {
        float sum = partial[0 * 256 + t] + partial[1 * 256 + t]
                  + partial[2 * 256 + t] + partial[3 * 256 + t];
        opart[((size_t)b * CHUNKS_ + chunk) * 256 + t] = sum;
    }
}

// ---------------- K_final: reduce chunk partials, normalize -----------------
// grid (B), block 256. t = h*64 + w.
__global__ __launch_bounds__(256) void k_final(const float* __restrict__ opart,
                                               const float* __restrict__ Spart,
                                               float* __restrict__ out) {
    const int t = threadIdx.x;
    const int b = blockIdx.x;
    const int h = t >> 6, l = t & 63;

    float sp = (l < CHUNKS_) ? Spart[(b * H_ + h) * CHUNKS_ + l] : 0.f;
    float S = waveReduceSum(sp);

    float acc = 0.f;
    #pragma unroll
    for (int c = 0; c < CHUNKS_; ++c)
        acc += opart[((size_t)b * CHUNKS_ + c) * 256 + t];   // coalesced

    out[b * (H_ * W_) + t] = acc / (S + EPS_);
}

extern "C" void kernel_launch(void* const* d_in, const int* in_sizes, int n_in,
                              void* d_out, int out_size, void* d_ws, size_t ws_size,
                              hipStream_t stream) {
    const float* mem  = (const float*)d_in[0];   // [B, N, W]
    const float* ctrl = (const float*)d_in[1];   // [B, 280]
    const float* prev = (const float*)d_in[2];   // [B, H, N]
    float* out = (float*)d_out;                  // [B, H, W] f32

    float* e     = (float*)d_ws;                          // 8 MiB
    float* Lpart = e + (size_t)B_ * H_ * N_;              // 256*128 floats
    float* Spart = Lpart + B_ * H_ * K1B_;                // 256*32 floats
    float* opart = Spart + B_ * H_ * CHUNKS_;             // 2 MiB

    k_scores<<<dim3(K1B_, B_), 256, 0, stream>>>(mem, ctrl, e, Lpart);
    k_fused <<<dim3(CHUNKS_, B_), 256, 0, stream>>>(mem, ctrl, prev, e, Lpart, Spart, opart);
    k_final <<<dim3(B_), 256, 0, stream>>>(opart, Spart, out);
}